// Round 12
// baseline (132.834 us; speedup 1.0000x reference)
//
#include <hip/hip_runtime.h>
#include <hip/hip_fp16.h>
#include <math.h>

#define NUM_VARS 64
#define KK       32
#define NUM_CATS 256
#define LL       4
#define EE       16384
#define NN       8192
#define CC       4
#define BB       1024
#define NUM_INPUT 2048              // NUM_VARS * KK
#define RES_ROWS  18432             // input + L0 + L1 resident in LDS
#define RES_BYTES (RES_ROWS * 8)    // 147456 (8 B/row = 4 cols fp16)
#define THREADS   1024
#define NPT       (NN / THREADS)    // 8 node-iters per thread per layer
// LDS: rows (147456 B) + red scratch (512 B) + cats (1024 B)
#define LDS_BYTES (RES_BYTES + 512 + 1024)

#define LOG2E 1.4426950408889634f
#define LN2   0.6931471805599453f

#if __has_builtin(__builtin_amdgcn_exp2f)
#define EXP2(x) __builtin_amdgcn_exp2f(x)
#else
#define EXP2(x) exp2f(x)
#endif
#if __has_builtin(__builtin_amdgcn_logf)
#define LOG2(x) __builtin_amdgcn_logf(x)
#else
#define LOG2(x) log2f(x)
#endif

// Flattened per-layer magnitude biases (log2 domain). Stored row = true - B.
#define B_IN  (-9.0f)
#define B_L0  (-18.0f)
#define B_L1  (-26.0f)
#define B_L2  (-31.0f)
#define B_RT  (-64.0f)   // root un-bias, applied exactly at the output

__device__ __forceinline__ float child_bias(int row) {
    if (row < NUM_INPUT) return B_IN;
    int l = (row - NUM_INPUT) >> 13;
    return l == 0 ? B_L0 : (l == 1 ? B_L1 : B_L2);
}

__device__ __forceinline__ __half2 u2h(unsigned u) {
    union { unsigned u; __half2 h; } c; c.u = u; return c.h;
}
__device__ __forceinline__ unsigned h2u(__half2 h) {
    union { __half2 h; unsigned u; } c; c.h = h; return c.u;
}

// ROCm 7.2 has no __hmax2 — emit the packed max directly (VOP3P).
__device__ __forceinline__ __half2 hmax2(__half2 a, __half2 b) {
    unsigned r, ua = h2u(a), ub = h2u(b);
    asm("v_pk_max_f16 %0, %1, %2" : "=v"(r) : "v"(ua), "v"(ub));
    return u2h(r);
}

// ---------------------------------------------------------------------------
// Prep: collapse sum_ch_ids -> prod_ids into 8 byte offsets (row*8) per node;
// weights -> base-2 domain, bias-folded, duplicated per column-pair as fp16x2
// words (uint4 = 4 children). root_logw folded into layer 3.
// ---------------------------------------------------------------------------
__global__ void prep_kernel(const int* __restrict__ prod_ids,    // L x E x 2
                            const int* __restrict__ sum_ch_ids,  // L x N x C
                            const float* __restrict__ sum_logw,  // L x N x C
                            const float* __restrict__ root_logw, // N
                            int4* __restrict__ recA,             // L*N x 2
                            uint4* __restrict__ recBh)           // L*N
{
    int idx = blockIdx.x * 64 + threadIdx.x;      // 0 .. L*N-1
    int l = idx >> 13;
    int n = idx & (NN - 1);
    const int*  sch  = sum_ch_ids + (size_t)idx * CC;
    const int2* prod = (const int2*)prod_ids + (size_t)l * EE;
    int2 p0 = prod[sch[0]];
    int2 p1 = prod[sch[1]];
    int2 p2 = prod[sch[2]];
    int2 p3 = prod[sch[3]];
    recA[(size_t)idx * 2]     = make_int4(p0.x << 3, p0.y << 3, p1.x << 3, p1.y << 3);
    recA[(size_t)idx * 2 + 1] = make_int4(p2.x << 3, p2.y << 3, p3.x << 3, p3.y << 3);

    const float nodeB[4] = {B_L0, B_L1, B_L2, B_RT};
    float r = (l == 3) ? root_logw[n] : 0.0f;
    const float* w = sum_logw + (size_t)idx * CC;
    float f0 = (w[0] + r) * LOG2E + child_bias(p0.x) + child_bias(p0.y) - nodeB[l];
    float f1 = (w[1] + r) * LOG2E + child_bias(p1.x) + child_bias(p1.y) - nodeB[l];
    float f2 = (w[2] + r) * LOG2E + child_bias(p2.x) + child_bias(p2.y) - nodeB[l];
    float f3 = (w[3] + r) * LOG2E + child_bias(p3.x) + child_bias(p3.y) - nodeB[l];
    recBh[idx] = make_uint4(h2u(__half2half2(__float2half_rn(f0))),
                            h2u(__half2half2(__float2half_rn(f1))),
                            h2u(__half2half2(__float2half_rn(f2))),
                            h2u(__half2half2(__float2half_rn(f3))));
}

// packed base-2 logsumexp of 4 (two columns per __half2 lane-pair)
__device__ __forceinline__ __half2 lse4h(__half2 x0, __half2 x1,
                                         __half2 x2, __half2 x3) {
    __half2 m = hmax2(hmax2(x0, x1), hmax2(x2, x3));
    __half2 s = __hadd2(__hadd2(h2exp2(__hsub2(x0, m)), h2exp2(__hsub2(x1, m))),
                        __hadd2(h2exp2(__hsub2(x2, m)), h2exp2(__hsub2(x3, m))));
    return __hadd2(m, h2log2(s));
}

typedef unsigned long long u64;

// 8 gathered children (u64 = 4 cols fp16) + packed weights -> node value
__device__ __forceinline__ uint2 node4h64(u64 h0, u64 h1, u64 h2, u64 h3,
                                          u64 h4, u64 h5, u64 h6, u64 h7,
                                          uint4 wu) {
    __half2 xa0 = __hadd2(__hadd2(u2h((unsigned)h0), u2h((unsigned)h1)), u2h(wu.x));
    __half2 xa1 = __hadd2(__hadd2(u2h((unsigned)h2), u2h((unsigned)h3)), u2h(wu.y));
    __half2 xa2 = __hadd2(__hadd2(u2h((unsigned)h4), u2h((unsigned)h5)), u2h(wu.z));
    __half2 xa3 = __hadd2(__hadd2(u2h((unsigned)h6), u2h((unsigned)h7)), u2h(wu.w));
    __half2 xb0 = __hadd2(__hadd2(u2h((unsigned)(h0 >> 32)), u2h((unsigned)(h1 >> 32))), u2h(wu.x));
    __half2 xb1 = __hadd2(__hadd2(u2h((unsigned)(h2 >> 32)), u2h((unsigned)(h3 >> 32))), u2h(wu.y));
    __half2 xb2 = __hadd2(__hadd2(u2h((unsigned)(h4 >> 32)), u2h((unsigned)(h5 >> 32))), u2h(wu.z));
    __half2 xb3 = __hadd2(__hadd2(u2h((unsigned)(h6 >> 32)), u2h((unsigned)(h7 >> 32))), u2h(wu.w));
    uint2 res;
    res.x = h2u(lse4h(xa0, xa1, xa2, xa3));
    res.y = h2u(lse4h(xb0, xb1, xb2, xb3));
    return res;
}

__device__ __forceinline__ u64 ld64(const float* lds, int off) {
    return *(const u64*)((const char*)lds + off);
}
__device__ __forceinline__ u64 ld64gb(uintptr_t lb, uintptr_t gb, unsigned off) {
    return *(const u64*)((off < (unsigned)RES_BYTES ? lb : gb) + off);
}

// Keep-alive: forces all 16 gather results live simultaneously -> compiler
// must issue all 16 ds_reads before one wait (batched MLP, not serialized).
#define KEEPALIVE16() \
    asm volatile("" : "+v"(h0), "+v"(h1), "+v"(h2),  "+v"(h3),  "+v"(h4),  "+v"(h5),  "+v"(h6),  "+v"(h7), \
                      "+v"(h8), "+v"(h9), "+v"(h10), "+v"(h11), "+v"(h12), "+v"(h13), "+v"(h14), "+v"(h15))

// gather+compute for a PAIR of nodes, children all in LDS
__device__ __forceinline__ void pair_lds(const float* lds,
        int4 a0, int4 a1, uint4 aw, int4 b0, int4 b1, uint4 bw,
        uint2& oa, uint2& ob) {
    u64 h0 = ld64(lds, a0.x), h1 = ld64(lds, a0.y),
        h2 = ld64(lds, a0.z), h3 = ld64(lds, a0.w),
        h4 = ld64(lds, a1.x), h5 = ld64(lds, a1.y),
        h6 = ld64(lds, a1.z), h7 = ld64(lds, a1.w),
        h8 = ld64(lds, b0.x), h9 = ld64(lds, b0.y),
        h10 = ld64(lds, b0.z), h11 = ld64(lds, b0.w),
        h12 = ld64(lds, b1.x), h13 = ld64(lds, b1.y),
        h14 = ld64(lds, b1.z), h15 = ld64(lds, b1.w);
    KEEPALIVE16();
    oa = node4h64(h0, h1, h2, h3, h4, h5, h6, h7, aw);
    ob = node4h64(h8, h9, h10, h11, h12, h13, h14, h15, bw);
}

// gather+compute for a PAIR of nodes, children in LDS or global (layer 3)
__device__ __forceinline__ void pair_mix(uintptr_t lb, uintptr_t gb,
        int4 a0, int4 a1, uint4 aw, int4 b0, int4 b1, uint4 bw,
        uint2& oa, uint2& ob) {
    u64 h0 = ld64gb(lb, gb, a0.x), h1 = ld64gb(lb, gb, a0.y),
        h2 = ld64gb(lb, gb, a0.z), h3 = ld64gb(lb, gb, a0.w),
        h4 = ld64gb(lb, gb, a1.x), h5 = ld64gb(lb, gb, a1.y),
        h6 = ld64gb(lb, gb, a1.z), h7 = ld64gb(lb, gb, a1.w),
        h8 = ld64gb(lb, gb, b0.x), h9 = ld64gb(lb, gb, b0.y),
        h10 = ld64gb(lb, gb, b0.z), h11 = ld64gb(lb, gb, b0.w),
        h12 = ld64gb(lb, gb, b1.x), h13 = ld64gb(lb, gb, b1.y),
        h14 = ld64gb(lb, gb, b1.z), h15 = ld64gb(lb, gb, b1.w);
    KEEPALIVE16();
    oa = node4h64(h0, h1, h2, h3, h4, h5, h6, h7, aw);
    ob = node4h64(h8, h9, h10, h11, h12, h13, h14, h15, bw);
}

#define LREC(i, R0, R1, RW) { int n_ = t + (i) * THREADS;           \
        R0 = ra[(size_t)n_ * 2]; R1 = ra[(size_t)n_ * 2 + 1]; RW = rb[n_]; }

// ---------------------------------------------------------------------------
// Mega-kernel: one block = FOUR batch columns (fp16x4 = 8 B per row).
// {input, L0, L1} resident in LDS; L2 streams to global; L3 via per-lane
// LDS/global select. Pairwise forced-batch gathers (keep-alive) in all
// layers; record loads staggered 2-3 pairs ahead. Packed fp16 math.
// ---------------------------------------------------------------------------
__global__ __launch_bounds__(THREADS, 4)
void circuit_kernel(const int* __restrict__ inputs,          // B x NUM_VARS
                    const float* __restrict__ input_logp,    // V x K x CATS
                    const int4* __restrict__ recA,           // L*N x 2
                    const uint4* __restrict__ recBh,         // L*N
                    uint2* __restrict__ gL2all,              // B/4 x NN
                    float* __restrict__ out)                 // B
{
    extern __shared__ float lds[];
    uint2* rows64 = (uint2*)lds;
    float* red  = lds + RES_BYTES / 4;          // 128 floats (16 waves x 8)
    int*   cats = (int*)(red + 128);            // 256 ints (4 cols x 64 vars)

    int b4 = blockIdx.x * 4;
    int t = threadIdx.x;
    uint2* g2 = gL2all + (size_t)blockIdx.x * NN;

    if (t < 256) cats[t] = inputs[(b4 + (t >> 6)) * NUM_VARS + (t & 63)];
    __syncthreads();

    // ---- input layer: 4 category gathers per row, pack to fp16x4
#pragma unroll
    for (int i = 0; i < NUM_INPUT / THREADS; ++i) {
        int idx = t + i * THREADS;
        int v = idx >> 5;
        const float* base = input_logp + (size_t)idx * NUM_CATS;
        float f0 = fmaf(base[cats[v]],        LOG2E, -B_IN);
        float f1 = fmaf(base[cats[64 + v]],   LOG2E, -B_IN);
        float f2 = fmaf(base[cats[128 + v]],  LOG2E, -B_IN);
        float f3 = fmaf(base[cats[192 + v]],  LOG2E, -B_IN);
        rows64[idx] = make_uint2(h2u(__floats2half2_rn(f0, f1)),
                                 h2u(__floats2half2_rn(f2, f3)));
    }
    __syncthreads();

    // ---- layers 0..1: pairwise forced-batch gather; store pass at end
    for (int l = 0; l < 2; ++l) {
        const int4*  ra = recA  + (size_t)l * NN * 2;
        const uint4* rb = recBh + (size_t)l * NN;
        uint2* dstl = rows64 + NUM_INPUT + l * NN;
        int4 A0, A1, B0, B1, C0, C1, D0, D1, E0, E1, F0, F1, G0, G1, H0, H1;
        uint4 AW, BW, CW, DW, EW, FW, GW, HW;
        uint2 o0, o1, o2, o3, o4, o5, o6, o7;
        LREC(0, A0, A1, AW) LREC(1, B0, B1, BW)
        LREC(2, C0, C1, CW) LREC(3, D0, D1, DW)
        pair_lds(lds, A0, A1, AW, B0, B1, BW, o0, o1);
        LREC(4, E0, E1, EW) LREC(5, F0, F1, FW)
        pair_lds(lds, C0, C1, CW, D0, D1, DW, o2, o3);
        LREC(6, G0, G1, GW) LREC(7, H0, H1, HW)
        pair_lds(lds, E0, E1, EW, F0, F1, FW, o4, o5);
        pair_lds(lds, G0, G1, GW, H0, H1, HW, o6, o7);
        dstl[t]               = o0; dstl[t + THREADS]     = o1;
        dstl[t + 2 * THREADS] = o2; dstl[t + 3 * THREADS] = o3;
        dstl[t + 4 * THREADS] = o4; dstl[t + 5 * THREADS] = o5;
        dstl[t + 6 * THREADS] = o6; dstl[t + 7 * THREADS] = o7;
        __syncthreads();
    }

    // ---- layer 2: pairwise gather, streams to global (no LDS-write alias)
    {
        const int4*  ra = recA  + (size_t)2 * NN * 2;
        const uint4* rb = recBh + (size_t)2 * NN;
        int4 A0, A1, B0, B1, C0, C1, D0, D1, E0, E1, F0, F1, G0, G1, H0, H1;
        uint4 AW, BW, CW, DW, EW, FW, GW, HW;
        uint2 o0, o1, o2, o3, o4, o5, o6, o7;
        LREC(0, A0, A1, AW) LREC(1, B0, B1, BW)
        LREC(2, C0, C1, CW) LREC(3, D0, D1, DW)
        pair_lds(lds, A0, A1, AW, B0, B1, BW, o0, o1);
        LREC(4, E0, E1, EW) LREC(5, F0, F1, FW)
        pair_lds(lds, C0, C1, CW, D0, D1, DW, o2, o3);
        LREC(6, G0, G1, GW) LREC(7, H0, H1, HW)
        pair_lds(lds, E0, E1, EW, F0, F1, FW, o4, o5);
        pair_lds(lds, G0, G1, GW, H0, H1, HW, o6, o7);
        g2[t]               = o0; g2[t + THREADS]     = o1;
        g2[t + 2 * THREADS] = o2; g2[t + 3 * THREADS] = o3;
        g2[t + 4 * THREADS] = o4; g2[t + 5 * THREADS] = o5;
        g2[t + 6 * THREADS] = o6; g2[t + 7 * THREADS] = o7;
        __syncthreads();   // drains global stores before L3 reads them
    }

    // ---- layer 3 + root accumulate; children from LDS or global-L2 rows
    {
        const int4*  ra = recA  + (size_t)3 * NN * 2;
        const uint4* rb = recBh + (size_t)3 * NN;
        uintptr_t lb = (uintptr_t)lds;
        uintptr_t gb = (uintptr_t)g2 - (uintptr_t)RES_BYTES;
        float m[4], s[4];
#pragma unroll
        for (int c = 0; c < 4; ++c) { m[c] = -INFINITY; s[c] = 0.0f; }

        int4 A0, A1, B0, B1, C0, C1, D0, D1, E0, E1, F0, F1, G0, G1, H0, H1;
        uint4 AW, BW, CW, DW, EW, FW, GW, HW;
        uint2 o0, o1, o2, o3, o4, o5, o6, o7;
        LREC(0, A0, A1, AW) LREC(1, B0, B1, BW)
        LREC(2, C0, C1, CW) LREC(3, D0, D1, DW)
        pair_mix(lb, gb, A0, A1, AW, B0, B1, BW, o0, o1);
        LREC(4, E0, E1, EW) LREC(5, F0, F1, FW)
        pair_mix(lb, gb, C0, C1, CW, D0, D1, DW, o2, o3);
        LREC(6, G0, G1, GW) LREC(7, H0, H1, HW)
        pair_mix(lb, gb, E0, E1, EW, F0, F1, FW, o4, o5);
        pair_mix(lb, gb, G0, G1, GW, H0, H1, HW, o6, o7);

        uint2 ov[8] = {o0, o1, o2, o3, o4, o5, o6, o7};
#pragma unroll
        for (int i = 0; i < 8; ++i) {
            float2 v01 = __half22float2(u2h(ov[i].x));
            float2 v23 = __half22float2(u2h(ov[i].y));
            float vv[4] = {v01.x, v01.y, v23.x, v23.y};
#pragma unroll
            for (int c = 0; c < 4; ++c) {
                float tm = fmaxf(m[c], vv[c]);
                s[c] = s[c] * EXP2(m[c] - tm) + EXP2(vv[c] - tm);
                m[c] = tm;
            }
        }
        // wave reduce (64 lanes), 4 columns
#pragma unroll
        for (int off = 32; off >= 1; off >>= 1) {
#pragma unroll
            for (int c = 0; c < 4; ++c) {
                float om = __shfl_xor(m[c], off), os = __shfl_xor(s[c], off);
                float tm = fmaxf(m[c], om);
                s[c] = s[c] * EXP2(m[c] - tm) + os * EXP2(om - tm);
                m[c] = tm;
            }
        }
        int wid = t >> 6;
        if ((t & 63) == 0) {
#pragma unroll
            for (int c = 0; c < 4; ++c) {
                red[wid * 8 + c * 2]     = m[c];
                red[wid * 8 + c * 2 + 1] = s[c];
            }
        }
        __syncthreads();
        if (t < 4) {                      // one thread per column
            int c = t;
            float M = -INFINITY;
#pragma unroll
            for (int wv = 0; wv < THREADS / 64; ++wv)
                M = fmaxf(M, red[wv * 8 + c * 2]);
            float S = 0.0f;
#pragma unroll
            for (int wv = 0; wv < THREADS / 64; ++wv)
                S += red[wv * 8 + c * 2 + 1] * EXP2(red[wv * 8 + c * 2] - M);
            out[b4 + c] = (M + LOG2(S) + B_RT) * LN2;
        }
    }
}

extern "C" void kernel_launch(void* const* d_in, const int* in_sizes, int n_in,
                              void* d_out, int out_size, void* d_ws, size_t ws_size,
                              hipStream_t stream) {
    const int*   inputs      = (const int*)d_in[0];
    const float* input_logp  = (const float*)d_in[1];
    const int*   prod_ids    = (const int*)d_in[2];
    const int*   sum_ch_ids  = (const int*)d_in[3];
    const float* sum_logw    = (const float*)d_in[4];
    const float* root_logw   = (const float*)d_in[5];
    float* out = (float*)d_out;

    int4*  recA   = (int4*)d_ws;                            // [L*N][2] int4 (1 MB)
    uint4* recBh  = (uint4*)(recA + (size_t)LL * NN * 2);   // [L*N] uint4 (512 KB)
    uint2* gL2all = (uint2*)(recBh + (size_t)LL * NN);      // [B/4][NN] uint2 (16 MB)

    static bool attr_done = false;
    if (!attr_done) {
        (void)hipFuncSetAttribute((const void*)circuit_kernel,
                                  hipFuncAttributeMaxDynamicSharedMemorySize,
                                  LDS_BYTES);
        attr_done = true;
    }

    prep_kernel<<<(LL * NN) / 64, 64, 0, stream>>>(
        prod_ids, sum_ch_ids, sum_logw, root_logw, recA, recBh);

    circuit_kernel<<<BB / 4, THREADS, LDS_BYTES, stream>>>(
        inputs, input_logp, recA, recBh, gL2all, out);
}

// Round 14
// 121.712 us; speedup vs baseline: 1.0914x; 1.0914x over previous
//
#include <hip/hip_runtime.h>
#include <hip/hip_fp16.h>
#include <math.h>

#define NUM_VARS 64
#define KK       32
#define NUM_CATS 256
#define LL       4
#define EE       16384
#define NN       8192
#define CC       4
#define BB       1024
#define NUM_INPUT 2048              // NUM_VARS * KK
#define RES_ROWS  18432             // input + L0 + L1 resident in LDS
#define RES_BYTES (RES_ROWS * 8)    // 147456 (8 B/row = 4 cols fp16)
#define THREADS   1024
#define NPT       (NN / THREADS)    // 8 node-iters per thread per layer
// LDS: rows (147456 B) + red scratch (512 B) + cats (1024 B)
#define LDS_BYTES (RES_BYTES + 512 + 1024)

#define LOG2E 1.4426950408889634f
#define LN2   0.6931471805599453f

#if __has_builtin(__builtin_amdgcn_exp2f)
#define EXP2(x) __builtin_amdgcn_exp2f(x)
#else
#define EXP2(x) exp2f(x)
#endif
#if __has_builtin(__builtin_amdgcn_logf)
#define LOG2(x) __builtin_amdgcn_logf(x)
#else
#define LOG2(x) log2f(x)
#endif

// Flattened per-layer magnitude biases (log2 domain). Stored row = true - B.
#define B_IN  (-9.0f)
#define B_L0  (-18.0f)
#define B_L1  (-26.0f)
#define B_L2  (-31.0f)
#define B_RT  (-64.0f)   // root un-bias, applied exactly at the output

__device__ __forceinline__ float child_bias(int row) {
    if (row < NUM_INPUT) return B_IN;
    int l = (row - NUM_INPUT) >> 13;
    return l == 0 ? B_L0 : (l == 1 ? B_L1 : B_L2);
}

__device__ __forceinline__ __half2 u2h(unsigned u) {
    union { unsigned u; __half2 h; } c; c.u = u; return c.h;
}
__device__ __forceinline__ unsigned h2u(__half2 h) {
    union { __half2 h; unsigned u; } c; c.h = h; return c.u;
}

// ROCm 7.2 has no __hmax2 — emit the packed max directly (VOP3P).
__device__ __forceinline__ __half2 hmax2(__half2 a, __half2 b) {
    unsigned r, ua = h2u(a), ub = h2u(b);
    asm("v_pk_max_f16 %0, %1, %2" : "=v"(r) : "v"(ua), "v"(ub));
    return u2h(r);
}

// ---------------------------------------------------------------------------
// Prep: collapse sum_ch_ids -> prod_ids into 8 byte offsets (row*8) per node;
// weights -> base-2 domain, bias-folded, duplicated per column-pair as fp16x2
// words (uint4 = 4 children). root_logw folded into layer 3.
// ---------------------------------------------------------------------------
__global__ void prep_kernel(const int* __restrict__ prod_ids,    // L x E x 2
                            const int* __restrict__ sum_ch_ids,  // L x N x C
                            const float* __restrict__ sum_logw,  // L x N x C
                            const float* __restrict__ root_logw, // N
                            int4* __restrict__ recA,             // L*N x 2
                            uint4* __restrict__ recBh)           // L*N
{
    int idx = blockIdx.x * 64 + threadIdx.x;      // 0 .. L*N-1
    int l = idx >> 13;
    int n = idx & (NN - 1);
    const int*  sch  = sum_ch_ids + (size_t)idx * CC;
    const int2* prod = (const int2*)prod_ids + (size_t)l * EE;
    int2 p0 = prod[sch[0]];
    int2 p1 = prod[sch[1]];
    int2 p2 = prod[sch[2]];
    int2 p3 = prod[sch[3]];
    recA[(size_t)idx * 2]     = make_int4(p0.x << 3, p0.y << 3, p1.x << 3, p1.y << 3);
    recA[(size_t)idx * 2 + 1] = make_int4(p2.x << 3, p2.y << 3, p3.x << 3, p3.y << 3);

    const float nodeB[4] = {B_L0, B_L1, B_L2, B_RT};
    float r = (l == 3) ? root_logw[n] : 0.0f;
    const float* w = sum_logw + (size_t)idx * CC;
    float f0 = (w[0] + r) * LOG2E + child_bias(p0.x) + child_bias(p0.y) - nodeB[l];
    float f1 = (w[1] + r) * LOG2E + child_bias(p1.x) + child_bias(p1.y) - nodeB[l];
    float f2 = (w[2] + r) * LOG2E + child_bias(p2.x) + child_bias(p2.y) - nodeB[l];
    float f3 = (w[3] + r) * LOG2E + child_bias(p3.x) + child_bias(p3.y) - nodeB[l];
    recBh[idx] = make_uint4(h2u(__half2half2(__float2half_rn(f0))),
                            h2u(__half2half2(__float2half_rn(f1))),
                            h2u(__half2half2(__float2half_rn(f2))),
                            h2u(__half2half2(__float2half_rn(f3))));
}

// packed base-2 logsumexp of 4 (two columns per __half2 lane-pair)
__device__ __forceinline__ __half2 lse4h(__half2 x0, __half2 x1,
                                         __half2 x2, __half2 x3) {
    __half2 m = hmax2(hmax2(x0, x1), hmax2(x2, x3));
    __half2 s = __hadd2(__hadd2(h2exp2(__hsub2(x0, m)), h2exp2(__hsub2(x1, m))),
                        __hadd2(h2exp2(__hsub2(x2, m)), h2exp2(__hsub2(x3, m))));
    return __hadd2(m, h2log2(s));
}

typedef unsigned long long u64;

// 8 gathered children (u64 = 4 cols fp16) + packed weights -> node value
__device__ __forceinline__ uint2 node4h64(u64 h0, u64 h1, u64 h2, u64 h3,
                                          u64 h4, u64 h5, u64 h6, u64 h7,
                                          uint4 wu) {
    __half2 xa0 = __hadd2(__hadd2(u2h((unsigned)h0), u2h((unsigned)h1)), u2h(wu.x));
    __half2 xa1 = __hadd2(__hadd2(u2h((unsigned)h2), u2h((unsigned)h3)), u2h(wu.y));
    __half2 xa2 = __hadd2(__hadd2(u2h((unsigned)h4), u2h((unsigned)h5)), u2h(wu.z));
    __half2 xa3 = __hadd2(__hadd2(u2h((unsigned)h6), u2h((unsigned)h7)), u2h(wu.w));
    __half2 xb0 = __hadd2(__hadd2(u2h((unsigned)(h0 >> 32)), u2h((unsigned)(h1 >> 32))), u2h(wu.x));
    __half2 xb1 = __hadd2(__hadd2(u2h((unsigned)(h2 >> 32)), u2h((unsigned)(h3 >> 32))), u2h(wu.y));
    __half2 xb2 = __hadd2(__hadd2(u2h((unsigned)(h4 >> 32)), u2h((unsigned)(h5 >> 32))), u2h(wu.z));
    __half2 xb3 = __hadd2(__hadd2(u2h((unsigned)(h6 >> 32)), u2h((unsigned)(h7 >> 32))), u2h(wu.w));
    uint2 res;
    res.x = h2u(lse4h(xa0, xa1, xa2, xa3));
    res.y = h2u(lse4h(xb0, xb1, xb2, xb3));
    return res;
}

// async LDS read: issue only; completion guaranteed by s_waitcnt lgkmcnt(N).
// volatile pins program order among the asm ops (counted-wait correctness).
__device__ __forceinline__ void dsr64(u64& dst, unsigned addr) {
    asm volatile("ds_read_b64 %0, %1" : "=v"(dst) : "v"(addr));
}
// counted wait + scheduling fence (rule #18: sched_barrier after lgkmcnt).
#define WAITL(n) do { asm volatile("s_waitcnt lgkmcnt(" #n ")" ::: "memory"); \
                      __builtin_amdgcn_sched_barrier(0); } while (0)

#define LREC(i, R0, R1, RW) { int n_ = t + (i) * THREADS;           \
        R0 = ra[(size_t)n_ * 2]; R1 = ra[(size_t)n_ * 2 + 1]; RW = rb[n_]; }

#define ISSUE8(S, R0, R1) \
    dsr64(h##S##0, lb32 + (unsigned)(R0).x); \
    dsr64(h##S##1, lb32 + (unsigned)(R0).y); \
    dsr64(h##S##2, lb32 + (unsigned)(R0).z); \
    dsr64(h##S##3, lb32 + (unsigned)(R0).w); \
    dsr64(h##S##4, lb32 + (unsigned)(R1).x); \
    dsr64(h##S##5, lb32 + (unsigned)(R1).y); \
    dsr64(h##S##6, lb32 + (unsigned)(R1).z); \
    dsr64(h##S##7, lb32 + (unsigned)(R1).w);

#define NODE(S, W) node4h64(h##S##0, h##S##1, h##S##2, h##S##3, \
                            h##S##4, h##S##5, h##S##6, h##S##7, (W))

// Depth-2 software pipeline over the 8 nodes/thread of one LDS-child layer:
// issue set A(i+1) -> wait lgkmcnt(8) (set of node i done, next in flight)
// -> compute node i. No ds_writes inside (they'd pollute the lgkm count).
#define LAYER_PIPE(STORE_STMT) { \
    int4 rA0, rA1, rB0, rB1; uint4 wA, wB; \
    u64 hA0,hA1,hA2,hA3,hA4,hA5,hA6,hA7; \
    u64 hB0,hB1,hB2,hB3,hB4,hB5,hB6,hB7; \
    uint2 o0,o1,o2,o3,o4,o5,o6,o7; \
    LREC(0, rA0, rA1, wA) ISSUE8(A, rA0, rA1) \
    LREC(1, rB0, rB1, wB) ISSUE8(B, rB0, rB1) \
    WAITL(8); o0 = NODE(A, wA); \
    LREC(2, rA0, rA1, wA) ISSUE8(A, rA0, rA1) \
    WAITL(8); o1 = NODE(B, wB); \
    LREC(3, rB0, rB1, wB) ISSUE8(B, rB0, rB1) \
    WAITL(8); o2 = NODE(A, wA); \
    LREC(4, rA0, rA1, wA) ISSUE8(A, rA0, rA1) \
    WAITL(8); o3 = NODE(B, wB); \
    LREC(5, rB0, rB1, wB) ISSUE8(B, rB0, rB1) \
    WAITL(8); o4 = NODE(A, wA); \
    LREC(6, rA0, rA1, wA) ISSUE8(A, rA0, rA1) \
    WAITL(8); o5 = NODE(B, wB); \
    LREC(7, rB0, rB1, wB) ISSUE8(B, rB0, rB1) \
    WAITL(8); o6 = NODE(A, wA); \
    WAITL(0); o7 = NODE(B, wB); \
    STORE_STMT }

// ---------------------------------------------------------------------------
// Mega-kernel: one block = FOUR batch columns (fp16x4 = 8 B per row).
// {input, L0, L1} resident in LDS; L2 streams to global; L3 via per-lane
// LDS/global select. Layers 0-2 use a counted-lgkmcnt depth-2 pipeline
// (inline-asm ds_read_b64) to hide LDS gather latency. Packed fp16 math.
// ---------------------------------------------------------------------------
__global__ __launch_bounds__(THREADS, 4)
void circuit_kernel(const int* __restrict__ inputs,          // B x NUM_VARS
                    const float* __restrict__ input_logp,    // V x K x CATS
                    const int4* __restrict__ recA,           // L*N x 2
                    const uint4* __restrict__ recBh,         // L*N
                    uint2* __restrict__ gL2all,              // B/4 x NN
                    float* __restrict__ out)                 // B
{
    extern __shared__ float lds[];
    uint2* rows64 = (uint2*)lds;
    float* red  = lds + RES_BYTES / 4;          // 128 floats (16 waves x 8)
    int*   cats = (int*)(red + 128);            // 256 ints (4 cols x 64 vars)

    int b4 = blockIdx.x * 4;
    int t = threadIdx.x;
    uint2* g2 = gL2all + (size_t)blockIdx.x * NN;
    // LDS byte address of the dynamic-shared base (flat->group truncation).
    const unsigned lb32 = (unsigned)(uintptr_t)lds;

    if (t < 256) cats[t] = inputs[(b4 + (t >> 6)) * NUM_VARS + (t & 63)];
    __syncthreads();

    // ---- input layer: 4 category gathers per row, pack to fp16x4
#pragma unroll
    for (int i = 0; i < NUM_INPUT / THREADS; ++i) {
        int idx = t + i * THREADS;
        int v = idx >> 5;
        const float* base = input_logp + (size_t)idx * NUM_CATS;
        float f0 = fmaf(base[cats[v]],        LOG2E, -B_IN);
        float f1 = fmaf(base[cats[64 + v]],   LOG2E, -B_IN);
        float f2 = fmaf(base[cats[128 + v]],  LOG2E, -B_IN);
        float f3 = fmaf(base[cats[192 + v]],  LOG2E, -B_IN);
        rows64[idx] = make_uint2(h2u(__floats2half2_rn(f0, f1)),
                                 h2u(__floats2half2_rn(f2, f3)));
    }
    __syncthreads();

    // ---- layers 0..1: pipelined gather; deferred LDS store pass
    for (int l = 0; l < 2; ++l) {
        const int4*  ra = recA  + (size_t)l * NN * 2;
        const uint4* rb = recBh + (size_t)l * NN;
        uint2* dstl = rows64 + NUM_INPUT + l * NN;
        LAYER_PIPE(
            dstl[t]               = o0; dstl[t + THREADS]     = o1;
            dstl[t + 2 * THREADS] = o2; dstl[t + 3 * THREADS] = o3;
            dstl[t + 4 * THREADS] = o4; dstl[t + 5 * THREADS] = o5;
            dstl[t + 6 * THREADS] = o6; dstl[t + 7 * THREADS] = o7;
        )
        __syncthreads();
    }

    // ---- layer 2: pipelined gather, streams to global
    {
        const int4*  ra = recA  + (size_t)2 * NN * 2;
        const uint4* rb = recBh + (size_t)2 * NN;
        LAYER_PIPE(
            g2[t]               = o0; g2[t + THREADS]     = o1;
            g2[t + 2 * THREADS] = o2; g2[t + 3 * THREADS] = o3;
            g2[t + 4 * THREADS] = o4; g2[t + 5 * THREADS] = o5;
            g2[t + 6 * THREADS] = o6; g2[t + 7 * THREADS] = o7;
        )
        __syncthreads();   // drains global stores before L3 reads them
    }

    // ---- layer 3 + root accumulate; children from LDS or global-L2 rows
    {
        const int4*  ra = recA  + (size_t)3 * NN * 2;
        const uint4* rb = recBh + (size_t)3 * NN;
        uintptr_t lb = (uintptr_t)lds;
        uintptr_t gb = (uintptr_t)g2 - (uintptr_t)RES_BYTES;
        float m[4], s[4];
#pragma unroll
        for (int c = 0; c < 4; ++c) { m[c] = -INFINITY; s[c] = 0.0f; }
#pragma unroll 2
        for (int i = 0; i < NPT; ++i) {
            int n = t + i * THREADS;
            int4 r0 = ra[(size_t)n * 2];
            int4 r1 = ra[(size_t)n * 2 + 1];
            uint4 wu = rb[n];
            u64 h[8];
            h[0] = *(const u64*)(((unsigned)r0.x < RES_BYTES ? lb : gb) + (unsigned)r0.x);
            h[1] = *(const u64*)(((unsigned)r0.y < RES_BYTES ? lb : gb) + (unsigned)r0.y);
            h[2] = *(const u64*)(((unsigned)r0.z < RES_BYTES ? lb : gb) + (unsigned)r0.z);
            h[3] = *(const u64*)(((unsigned)r0.w < RES_BYTES ? lb : gb) + (unsigned)r0.w);
            h[4] = *(const u64*)(((unsigned)r1.x < RES_BYTES ? lb : gb) + (unsigned)r1.x);
            h[5] = *(const u64*)(((unsigned)r1.y < RES_BYTES ? lb : gb) + (unsigned)r1.y);
            h[6] = *(const u64*)(((unsigned)r1.z < RES_BYTES ? lb : gb) + (unsigned)r1.z);
            h[7] = *(const u64*)(((unsigned)r1.w < RES_BYTES ? lb : gb) + (unsigned)r1.w);
            uint2 res = node4h64(h[0], h[1], h[2], h[3], h[4], h[5], h[6], h[7], wu);
            float2 v01 = __half22float2(u2h(res.x));
            float2 v23 = __half22float2(u2h(res.y));
            float vv[4] = {v01.x, v01.y, v23.x, v23.y};
#pragma unroll
            for (int c = 0; c < 4; ++c) {
                float tm = fmaxf(m[c], vv[c]);
                s[c] = s[c] * EXP2(m[c] - tm) + EXP2(vv[c] - tm);
                m[c] = tm;
            }
        }
        // wave reduce (64 lanes), 4 columns
#pragma unroll
        for (int off = 32; off >= 1; off >>= 1) {
#pragma unroll
            for (int c = 0; c < 4; ++c) {
                float om = __shfl_xor(m[c], off), os = __shfl_xor(s[c], off);
                float tm = fmaxf(m[c], om);
                s[c] = s[c] * EXP2(m[c] - tm) + os * EXP2(om - tm);
                m[c] = tm;
            }
        }
        int wid = t >> 6;
        if ((t & 63) == 0) {
#pragma unroll
            for (int c = 0; c < 4; ++c) {
                red[wid * 8 + c * 2]     = m[c];
                red[wid * 8 + c * 2 + 1] = s[c];
            }
        }
        __syncthreads();
        if (t < 4) {                      // one thread per column
            int c = t;
            float M = -INFINITY;
#pragma unroll
            for (int wv = 0; wv < THREADS / 64; ++wv)
                M = fmaxf(M, red[wv * 8 + c * 2]);
            float S = 0.0f;
#pragma unroll
            for (int wv = 0; wv < THREADS / 64; ++wv)
                S += red[wv * 8 + c * 2 + 1] * EXP2(red[wv * 8 + c * 2] - M);
            out[b4 + c] = (M + LOG2(S) + B_RT) * LN2;
        }
    }
}

extern "C" void kernel_launch(void* const* d_in, const int* in_sizes, int n_in,
                              void* d_out, int out_size, void* d_ws, size_t ws_size,
                              hipStream_t stream) {
    const int*   inputs      = (const int*)d_in[0];
    const float* input_logp  = (const float*)d_in[1];
    const int*   prod_ids    = (const int*)d_in[2];
    const int*   sum_ch_ids  = (const int*)d_in[3];
    const float* sum_logw    = (const float*)d_in[4];
    const float* root_logw   = (const float*)d_in[5];
    float* out = (float*)d_out;

    int4*  recA   = (int4*)d_ws;                            // [L*N][2] int4 (1 MB)
    uint4* recBh  = (uint4*)(recA + (size_t)LL * NN * 2);   // [L*N] uint4 (512 KB)
    uint2* gL2all = (uint2*)(recBh + (size_t)LL * NN);      // [B/4][NN] uint2 (16 MB)

    static bool attr_done = false;
    if (!attr_done) {
        (void)hipFuncSetAttribute((const void*)circuit_kernel,
                                  hipFuncAttributeMaxDynamicSharedMemorySize,
                                  LDS_BYTES);
        attr_done = true;
    }

    prep_kernel<<<(LL * NN) / 64, 64, 0, stream>>>(
        prod_ids, sum_ch_ids, sum_logw, root_logw, recA, recBh);

    circuit_kernel<<<BB / 4, THREADS, LDS_BYTES, stream>>>(
        inputs, input_logp, recA, recBh, gL2all, out);
}